// Round 1
// baseline (1996.323 us; speedup 1.0000x reference)
//
#include <hip/hip_runtime.h>
#include <hip/hip_bf16.h>

#define FLT_BIG 3.0e38f

// ---------------------------------------------------------------------------
// kNN: for each (b,p) query (query = xyz[b,:,p], p < P), find K nearest of the
// first N_pts points of xyz[b], by d2 = xs + ys - 2*dot (matches reference).
// One block (256 thr) per query. d2 staged in dynamic LDS; K rounds of argmin.
// Tie-break: lower index wins (matches jax.lax.top_k).
// ---------------------------------------------------------------------------
__global__ void knn_kernel(const float* __restrict__ x, int N_pts, int K, int P,
                           int* __restrict__ idx_out) {
    int bp = blockIdx.x;
    int b = bp / P, p = bp - b * P;
    const float* xyz = x + (size_t)b * 24576;  // (6,4096) per batch; xyz = ch 0..2
    extern __shared__ float d2[];
    __shared__ float wval[4];
    __shared__ int widx[4];
    int t = threadIdx.x;
    float qx = xyz[p], qy = xyz[4096 + p], qz = xyz[8192 + p];
    float xs = (qx * qx + qy * qy) + qz * qz;
    for (int n = t; n < N_pts; n += 256) {
        float yx = xyz[n], yy = xyz[4096 + n], yz = xyz[8192 + n];
        float ys = (yx * yx + yy * yy) + yz * yz;
        float dot = (qx * yx + qy * yy) + qz * yz;
        d2[n] = (xs + ys) - 2.0f * dot;
    }
    __syncthreads();
    int lane = t & 63, wv = t >> 6;
    for (int r = 0; r < K; ++r) {
        float best = FLT_BIG;
        int bi = 0x7fffffff;
        for (int n = t; n < N_pts; n += 256) {
            float v = d2[n];
            if (v < best) { best = v; bi = n; }  // strict <: lowest n kept
        }
#pragma unroll
        for (int s = 32; s > 0; s >>= 1) {
            float ov = __shfl_down(best, s);
            int oi = __shfl_down(bi, s);
            if (ov < best || (ov == best && oi < bi)) { best = ov; bi = oi; }
        }
        if (lane == 0) { wval[wv] = best; widx[wv] = bi; }
        __syncthreads();
        if (t == 0) {
            float bb = wval[0]; int ii = widx[0];
            for (int w = 1; w < 4; ++w)
                if (wval[w] < bb || (wval[w] == bb && widx[w] < ii)) { bb = wval[w]; ii = widx[w]; }
            idx_out[(size_t)bp * K + r] = ii;
            d2[ii] = FLT_BIG;
        }
        __syncthreads();
    }
}

// ---------------------------------------------------------------------------
// SA1 fused gather + MLP(6->64->64->128) + maxpool over k=32.
// One block (256 thr) per (b,p), p < 512.
// ---------------------------------------------------------------------------
__global__ void sa1_mlp_kernel(const float* __restrict__ x, const int* __restrict__ idx1,
                               const float* __restrict__ w1, const float* __restrict__ b1,
                               const float* __restrict__ w2, const float* __restrict__ b2,
                               const float* __restrict__ w3, const float* __restrict__ b3,
                               float* __restrict__ p1out) {
    int bp = blockIdx.x;
    int b = bp >> 9, p = bp & 511;
    __shared__ float feat[6][32];
    __shared__ float h1[64][32];
    __shared__ float h2[64][32];
    __shared__ int nbr[32];
    __shared__ float mx[128][2];
    const float* xb = x + (size_t)b * 24576;
    int t = threadIdx.x;
    if (t < 32) nbr[t] = idx1[(size_t)bp * 32 + t];
    __syncthreads();
    if (t < 192) {
        int c = t >> 5, k = t & 31;
        int n = nbr[k];
        float v = xb[c * 4096 + n];
        if (c < 3) v -= xb[c * 4096 + p];
        feat[c][k] = v;
    }
    __syncthreads();
    {   // h1: 64 o x 32 k
        int o = t >> 2, kg = t & 3;
        float acc[8];
        float bias = b1[o];
#pragma unroll
        for (int j = 0; j < 8; j++) acc[j] = bias;
#pragma unroll
        for (int c = 0; c < 6; c++) {
            float w = w1[o * 6 + c];
#pragma unroll
            for (int j = 0; j < 8; j++) acc[j] += w * feat[c][kg * 8 + j];
        }
#pragma unroll
        for (int j = 0; j < 8; j++) h1[o][kg * 8 + j] = fmaxf(acc[j], 0.f);
    }
    __syncthreads();
    {   // h2: 64 x 32
        int o = t >> 2, kg = t & 3;
        float acc[8];
        float bias = b2[o];
#pragma unroll
        for (int j = 0; j < 8; j++) acc[j] = bias;
        for (int c = 0; c < 64; c++) {
            float w = w2[o * 64 + c];
#pragma unroll
            for (int j = 0; j < 8; j++) acc[j] += w * h1[c][kg * 8 + j];
        }
#pragma unroll
        for (int j = 0; j < 8; j++) h2[o][kg * 8 + j] = fmaxf(acc[j], 0.f);
    }
    __syncthreads();
    {   // h3: 128 x 32 + local max
        int o = t >> 1, kg = t & 1;
        float acc[16];
        float bias = b3[o];
#pragma unroll
        for (int j = 0; j < 16; j++) acc[j] = bias;
        for (int c = 0; c < 64; c++) {
            float w = w3[o * 64 + c];
#pragma unroll
            for (int j = 0; j < 16; j++) acc[j] += w * h2[c][kg * 16 + j];
        }
        float m = acc[0];
#pragma unroll
        for (int j = 1; j < 16; j++) m = fmaxf(m, acc[j]);
        mx[o][kg] = m;
    }
    __syncthreads();
    if (t < 128)
        p1out[((size_t)b * 128 + t) * 512 + p] = fmaxf(mx[t][0], mx[t][1]);
}

// ---------------------------------------------------------------------------
// SA2 fused gather + MLP(131->128->128->256) + maxpool over k=64.
// One block (512 thr) per (b,p), p < 128. k processed in two halves of 32 to
// fit LDS (<64KB). bufA holds feat-half then h2; bufB holds h1.
// ---------------------------------------------------------------------------
__global__ void sa2_mlp_kernel(const float* __restrict__ x, const float* __restrict__ p1,
                               const int* __restrict__ idx2,
                               const float* __restrict__ w1, const float* __restrict__ b1,
                               const float* __restrict__ w2, const float* __restrict__ b2,
                               const float* __restrict__ w3, const float* __restrict__ b3,
                               float* __restrict__ p2out) {
    int bp = blockIdx.x;
    int b = bp >> 7, p = bp & 127;
    __shared__ float bufA[131 * 32];
    __shared__ float bufB[128 * 32];
    __shared__ int nbr[64];
    __shared__ float mx[256][2];
    const float* xb = x + (size_t)b * 24576;
    const float* p1b = p1 + (size_t)b * 65536;
    int t = threadIdx.x;
    if (t < 64) nbr[t] = idx2[(size_t)bp * 64 + t];
    float qx = xb[p], qy = xb[4096 + p], qz = xb[8192 + p];
    float runmax = -FLT_BIG;
    for (int half = 0; half < 2; ++half) {
        __syncthreads();
        for (int id = t; id < 131 * 32; id += 512) {
            int c = id >> 5, kk = id & 31;
            int n = nbr[half * 32 + kk];
            float v;
            if (c == 0) v = xb[n] - qx;
            else if (c == 1) v = xb[4096 + n] - qy;
            else if (c == 2) v = xb[8192 + n] - qz;
            else v = p1b[(size_t)(c - 3) * 512 + n];
            bufA[c * 32 + kk] = v;
        }
        __syncthreads();
        {   // h1: 128 o x 32 k
            int o = t >> 2, kg = t & 3;
            float acc[8];
            float bias = b1[o];
#pragma unroll
            for (int j = 0; j < 8; j++) acc[j] = bias;
            for (int c = 0; c < 131; c++) {
                float w = w1[o * 131 + c];
                const float* f = &bufA[c * 32 + kg * 8];
#pragma unroll
                for (int j = 0; j < 8; j++) acc[j] += w * f[j];
            }
            float* h = &bufB[o * 32 + kg * 8];
#pragma unroll
            for (int j = 0; j < 8; j++) h[j] = fmaxf(acc[j], 0.f);
        }
        __syncthreads();
        {   // h2: 128 x 32 -> bufA (feat dead)
            int o = t >> 2, kg = t & 3;
            float acc[8];
            float bias = b2[o];
#pragma unroll
            for (int j = 0; j < 8; j++) acc[j] = bias;
            for (int c = 0; c < 128; c++) {
                float w = w2[o * 128 + c];
                const float* f = &bufB[c * 32 + kg * 8];
#pragma unroll
                for (int j = 0; j < 8; j++) acc[j] += w * f[j];
            }
            float* h = &bufA[o * 32 + kg * 8];
#pragma unroll
            for (int j = 0; j < 8; j++) h[j] = fmaxf(acc[j], 0.f);
        }
        __syncthreads();
        {   // h3: 256 o x 32 k + running max
            int o = t >> 1, kg = t & 1;
            float acc[16];
            float bias = b3[o];
#pragma unroll
            for (int j = 0; j < 16; j++) acc[j] = bias;
            for (int c = 0; c < 128; c++) {
                float w = w3[o * 128 + c];
                const float* f = &bufA[c * 32 + kg * 16];
#pragma unroll
                for (int j = 0; j < 16; j++) acc[j] += w * f[j];
            }
            float m = acc[0];
#pragma unroll
            for (int j = 1; j < 16; j++) m = fmaxf(m, acc[j]);
            runmax = fmaxf(runmax, m);
        }
    }
    {
        int o = t >> 1, kg = t & 1;
        mx[o][kg] = runmax;
    }
    __syncthreads();
    if (t < 256) p2out[((size_t)b * 256 + t) * 128 + p] = fmaxf(mx[t][0], mx[t][1]);
}

// ---------------------------------------------------------------------------
// SA3 layers as weight-tiled batched GEMM over the 128 points of each batch:
// out[b][o][p] = act(bias[o] + sum_c W[o*wstride + woff + c] * in[b][c][p])
// Grid: B * (Cout/64) blocks, 256 thr. Block computes a 64(o) x 128(p) tile.
// Cin must be a multiple of 64.
// ---------------------------------------------------------------------------
__global__ void mlp128_kernel(const float* __restrict__ in, const float* __restrict__ W,
                              const float* __restrict__ bias, float* __restrict__ out,
                              int Cin, int Cout, int relu, int wstride, int woff) {
    int bid = blockIdx.x;
    int tiles = Cout >> 6;
    int b = bid / tiles, ot = bid - b * tiles;
    int o0 = ot << 6;
    __shared__ float ins[64][128];
    int t = threadIdx.x;
    int o = o0 + (t >> 2), pg = t & 3;
    float acc[32];
    float bv = bias[o];
#pragma unroll
    for (int j = 0; j < 32; j++) acc[j] = bv;
    for (int c0 = 0; c0 < Cin; c0 += 64) {
        __syncthreads();
        for (int id = t; id < 64 * 128; id += 256) {
            int c = id >> 7, p = id & 127;
            ins[c][p] = in[((size_t)b * Cin + c0 + c) * 128 + p];
        }
        __syncthreads();
        for (int c = 0; c < 64; ++c) {
            float w = W[(size_t)o * wstride + woff + c0 + c];
            const float* f = &ins[c][pg * 32];
#pragma unroll
            for (int j = 0; j < 32; j++) acc[j] += w * f[j];
        }
    }
#pragma unroll
    for (int j = 0; j < 32; j++) {
        float v = acc[j];
        if (relu) v = fmaxf(v, 0.f);
        out[((size_t)b * Cout + o) * 128 + pg * 32 + j] = v;
    }
}

// ---------------------------------------------------------------------------
// Head: g[b][o] = max_p p3[b][o][p]; then FC 1024->512->256->40.
// One block (256 thr) per batch.
// ---------------------------------------------------------------------------
__global__ void head_kernel(const float* __restrict__ p3,
                            const float* __restrict__ fw1, const float* __restrict__ fb1,
                            const float* __restrict__ fw2, const float* __restrict__ fb2,
                            const float* __restrict__ fw3, const float* __restrict__ fb3,
                            float* __restrict__ out) {
    int b = blockIdx.x;
    int t = threadIdx.x;
    __shared__ float g[1024];
    __shared__ float h1[512];
    __shared__ float h2[256];
    const float* p3b = p3 + (size_t)b * 1024 * 128;
    for (int oo = 0; oo < 4; oo++) {
        int o = t + oo * 256;
        const float* row = p3b + (size_t)o * 128;
        float m = row[0];
        for (int p = 1; p < 128; p++) m = fmaxf(m, row[p]);
        g[o] = m;
    }
    __syncthreads();
    for (int oo = 0; oo < 2; oo++) {
        int o = t + oo * 256;
        float acc = fb1[o];
        const float* wr = fw1 + (size_t)o * 1024;
        for (int c = 0; c < 1024; c++) acc += wr[c] * g[c];
        h1[o] = fmaxf(acc, 0.f);
    }
    __syncthreads();
    {
        float acc = fb2[t];
        const float* wr = fw2 + (size_t)t * 512;
        for (int c = 0; c < 512; c++) acc += wr[c] * h1[c];
        h2[t] = fmaxf(acc, 0.f);
    }
    __syncthreads();
    if (t < 40) {
        float acc = fb3[t];
        const float* wr = fw3 + (size_t)t * 256;
        for (int c = 0; c < 256; c++) acc += wr[c] * h2[c];
        out[b * 40 + t] = acc;
    }
}

extern "C" void kernel_launch(void* const* d_in, const int* in_sizes, int n_in,
                              void* d_out, int out_size, void* d_ws, size_t ws_size,
                              hipStream_t stream) {
    const float* x      = (const float*)d_in[0];
    const float* sa1_w1 = (const float*)d_in[1];
    const float* sa1_b1 = (const float*)d_in[2];
    const float* sa1_w2 = (const float*)d_in[3];
    const float* sa1_b2 = (const float*)d_in[4];
    const float* sa1_w3 = (const float*)d_in[5];
    const float* sa1_b3 = (const float*)d_in[6];
    const float* sa2_w1 = (const float*)d_in[7];
    const float* sa2_b1 = (const float*)d_in[8];
    const float* sa2_w2 = (const float*)d_in[9];
    const float* sa2_b2 = (const float*)d_in[10];
    const float* sa2_w3 = (const float*)d_in[11];
    const float* sa2_b3 = (const float*)d_in[12];
    const float* sa3_w1 = (const float*)d_in[13];
    const float* sa3_b1 = (const float*)d_in[14];
    const float* sa3_w2 = (const float*)d_in[15];
    const float* sa3_b2 = (const float*)d_in[16];
    const float* sa3_w3 = (const float*)d_in[17];
    const float* sa3_b3 = (const float*)d_in[18];
    const float* fc1_w  = (const float*)d_in[19];
    const float* fc1_b  = (const float*)d_in[20];
    const float* fc2_w  = (const float*)d_in[21];
    const float* fc2_b  = (const float*)d_in[22];
    const float* fc3_w  = (const float*)d_in[23];
    const float* fc3_b  = (const float*)d_in[24];

    char* ws = (char*)d_ws;
    int*   idx1 = (int*)  (ws + (size_t)(0)  * 1048576);  //  2 MB: (32,512,32) int
    float* p1   = (float*)(ws + (size_t)(2)  * 1048576);  //  8 MB: (32,128,512)
    int*   idx2 = (int*)  (ws + (size_t)(10) * 1048576);  //  1 MB: (32,128,64) int
    float* p2   = (float*)(ws + (size_t)(11) * 1048576);  //  4 MB: (32,256,128)
    float* h1s  = (float*)(ws + (size_t)(15) * 1048576);  //  4 MB: (32,256,128)
    float* h2s  = (float*)(ws + (size_t)(19) * 1048576);  //  8 MB: (32,512,128)
    float* p3   = (float*)(ws + (size_t)(27) * 1048576);  // 16 MB: (32,1024,128)

    // SA1
    knn_kernel<<<32 * 512, 256, 4096 * 4, stream>>>(x, 4096, 32, 512, idx1);
    sa1_mlp_kernel<<<32 * 512, 256, 0, stream>>>(x, idx1, sa1_w1, sa1_b1, sa1_w2, sa1_b2,
                                                 sa1_w3, sa1_b3, p1);
    // SA2
    knn_kernel<<<32 * 128, 256, 512 * 4, stream>>>(x, 512, 64, 128, idx2);
    sa2_mlp_kernel<<<32 * 128, 512, 0, stream>>>(x, p1, idx2, sa2_w1, sa2_b1, sa2_w2, sa2_b2,
                                                 sa2_w3, sa2_b3, p2);
    // SA3 (nsample=1 => neighbor is self, grouped_xyz == 0: skip first 3 weight cols)
    mlp128_kernel<<<32 * 4, 256, 0, stream>>>(p2, sa3_w1, sa3_b1, h1s, 256, 256, 1, 259, 3);
    mlp128_kernel<<<32 * 8, 256, 0, stream>>>(h1s, sa3_w2, sa3_b2, h2s, 256, 512, 1, 256, 0);
    mlp128_kernel<<<32 * 16, 256, 0, stream>>>(h2s, sa3_w3, sa3_b3, p3, 512, 1024, 0, 512, 0);
    // Head
    head_kernel<<<32, 256, 0, stream>>>(p3, fc1_w, fc1_b, fc2_w, fc2_b, fc3_w, fc3_b,
                                        (float*)d_out);
}

// Round 2
// 1398.358 us; speedup vs baseline: 1.4276x; 1.4276x over previous
//
#include <hip/hip_runtime.h>
#include <hip/hip_bf16.h>

#define FLT_BIG 3.0e38f

// ---------------------------------------------------------------------------
// kNN via radix select. Only the SET of K nearest matters (downstream max-
// pools over k), with boundary ties broken by lower index — equivalent to
// jax.lax.top_k on -d2. Keys: monotonic uint of fp32 d2 (exact same d2
// arithmetic as the reference), tie-break (key, idx) lexicographic.
// One block (256 thr) per query.
// ---------------------------------------------------------------------------
__global__ __launch_bounds__(256) void knn_select_kernel(
    const float* __restrict__ x, int N_pts, int K, int P, int* __restrict__ idx_out) {
    int bp = blockIdx.x;
    int b = bp / P, p = bp - b * P;
    const float* xyz = x + (size_t)b * 24576;
    __shared__ unsigned int keys[4096];
    __shared__ unsigned int hist[2048];
    __shared__ unsigned int scanbuf[256];
    __shared__ unsigned int candK[512];
    __shared__ int candI[512];
    __shared__ int outIdx[64];
    __shared__ int sBM[2];
    __shared__ unsigned int cnts[2];
    __shared__ unsigned int wK[4];
    __shared__ int wI[4];
    int t = threadIdx.x;
    for (int i = t; i < 2048; i += 256) hist[i] = 0u;
    if (t < 2) cnts[t] = 0u;
    float qx = xyz[p], qy = xyz[4096 + p], qz = xyz[8192 + p];
    float xs = (qx * qx + qy * qy) + qz * qz;
    __syncthreads();
    for (int n = t; n < N_pts; n += 256) {
        float yx = xyz[n], yy = xyz[4096 + n], yz = xyz[8192 + n];
        float ys = (yx * yx + yy * yy) + yz * yz;
        float dot = (qx * yx + qy * yy) + qz * yz;
        float d2 = (xs + ys) - 2.0f * dot;
        unsigned int k = __float_as_uint(d2);
        k = (k & 0x80000000u) ? ~k : (k | 0x80000000u);
        keys[n] = k;
        atomicAdd(&hist[k >> 21], 1u);
    }
    __syncthreads();
    unsigned int h8[8], mysum = 0u;
#pragma unroll
    for (int i = 0; i < 8; i++) { h8[i] = hist[t * 8 + i]; mysum += h8[i]; }
    scanbuf[t] = mysum;
    __syncthreads();
    for (int s = 1; s < 256; s <<= 1) {
        unsigned int v = (t >= s) ? scanbuf[t - s] : 0u;
        __syncthreads();
        scanbuf[t] += v;
        __syncthreads();
    }
    unsigned int cum = scanbuf[t] - mysum;
#pragma unroll
    for (int i = 0; i < 8; i++) {
        if (cum < (unsigned)K && cum + h8[i] >= (unsigned)K) { sBM[0] = t * 8 + i; sBM[1] = (int)cum; }
        cum += h8[i];
    }
    __syncthreads();
    int B = sBM[0], m = sBM[1], r = K - m;
    for (int n = t; n < N_pts; n += 256) {
        unsigned int k = keys[n];
        int bin = (int)(k >> 21);
        if (bin < B) {
            outIdx[atomicAdd(&cnts[0], 1u)] = n;
        } else if (bin == B) {
            unsigned int ci = atomicAdd(&cnts[1], 1u);
            if (ci < 512u) { candK[ci] = k; candI[ci] = n; }
        }
    }
    __syncthreads();
    int nc = (int)cnts[1];
    if (nc <= 512) {
        for (int ci = t; ci < nc; ci += 256) {
            unsigned int ki = candK[ci];
            int ii = candI[ci];
            int rank = 0;
            for (int j = 0; j < nc; j++) {
                unsigned int kj = candK[j];
                rank += (kj < ki || (kj == ki && candI[j] < ii)) ? 1 : 0;
            }
            if (rank < r) outIdx[m + rank] = ii;
        }
    } else {
        // fallback (never hit for benign data): r rounds of argmin over bin B
        for (int rr = 0; rr < r; ++rr) {
            unsigned int best = 0xFFFFFFFFu;
            int bi = 0x7fffffff;
            for (int n = t; n < N_pts; n += 256) {
                unsigned int k2 = keys[n];
                if ((int)(k2 >> 21) == B && (k2 < best || (k2 == best && n < bi))) { best = k2; bi = n; }
            }
#pragma unroll
            for (int s = 32; s > 0; s >>= 1) {
                unsigned int ov = (unsigned int)__shfl_down((int)best, s);
                int oi = __shfl_down(bi, s);
                if (ov < best || (ov == best && oi < bi)) { best = ov; bi = oi; }
            }
            int lane = t & 63, wv = t >> 6;
            if (lane == 0) { wK[wv] = best; wI[wv] = bi; }
            __syncthreads();
            if (t == 0) {
                unsigned int bb = wK[0];
                int ii = wI[0];
                for (int w = 1; w < 4; ++w)
                    if (wK[w] < bb || (wK[w] == bb && wI[w] < ii)) { bb = wK[w]; ii = wI[w]; }
                outIdx[m + rr] = ii;
                keys[ii] = 0xFFFFFFFFu;
            }
            __syncthreads();
        }
    }
    __syncthreads();
    if (t < K) idx_out[(size_t)bp * K + t] = outIdx[t];
}

// ---------------------------------------------------------------------------
// SA1 precompute: A1t[b][n][o] = b1[o] + sum_c w1[o][c] * x[b][c][n]  (c=0..5)
// n-major so the MLP kernel can gather coalesced rows. Grid 32*32, 256 thr.
// ---------------------------------------------------------------------------
__global__ __launch_bounds__(256) void sa1_pre_kernel(
    const float* __restrict__ x, const float* __restrict__ w1, const float* __restrict__ b1,
    float* __restrict__ a1t) {
    int bid = blockIdx.x;
    int b = bid >> 5, nt = bid & 31, n0 = nt << 7;
    __shared__ float xsh[6 * 128];
    __shared__ float wt[6 * 68];
    const float* xb = x + (size_t)b * 24576;
    int t = threadIdx.x;
    for (int id = t; id < 768; id += 256) {
        int c = id >> 7, n = id & 127;
        xsh[c * 128 + n] = xb[c * 4096 + n0 + n];
    }
    for (int id = t; id < 384; id += 256) {
        int c = id >> 6, o = id & 63;
        wt[c * 68 + o] = w1[o * 6 + c];
    }
    __syncthreads();
    int o = t & 63, ng = t >> 6;
    float acc[32];
    float bias = b1[o];
#pragma unroll
    for (int j = 0; j < 32; j++) acc[j] = bias;
    for (int c = 0; c < 6; c++) {
        float w = wt[c * 68 + o];
        const float* f = &xsh[c * 128 + ng * 32];
#pragma unroll
        for (int j = 0; j < 32; j++) acc[j] += w * f[j];
    }
#pragma unroll
    for (int j = 0; j < 32; j++)
        a1t[((size_t)b * 4096 + n0 + ng * 32 + j) * 64 + o] = acc[j];
}

// ---------------------------------------------------------------------------
// SA1 MLP: h1 = relu(A1t[nbr] + D1[p]); L2 64->64 relu; L3 64->128; max over k.
// Block = 2 query points (64 columns). 256 thr. p1 output c-major (b,128,512).
// ---------------------------------------------------------------------------
__global__ __launch_bounds__(256) void sa1_mlp_kernel(
    const float* __restrict__ x, const float* __restrict__ a1t,
    const int* __restrict__ idx1, const float* __restrict__ w1,
    const float* __restrict__ w2, const float* __restrict__ b2,
    const float* __restrict__ w3, const float* __restrict__ b3,
    float* __restrict__ p1) {
    int bp = blockIdx.x;  // 32*256
    int b = bp >> 8, pp = bp & 255, p0 = pp * 2;
    __shared__ float h1[64 * 64];
    __shared__ float h2[64 * 64];
    __shared__ float wt[2][16 * 132];
    __shared__ float mx[128 * 9];
    __shared__ float dsh[128];
    __shared__ int nbr[64];
    const float* xb = x + (size_t)b * 24576;
    int t = threadIdx.x;
    if (t < 64) nbr[t] = idx1[((size_t)b * 512 + p0) * 32 + t];
    if (t < 128) {
        int ps = t >> 6, o = t & 63;
        float qx = xb[p0 + ps], qy = xb[4096 + p0 + ps], qz = xb[8192 + p0 + ps];
        dsh[t] = -(w1[o * 6 + 0] * qx + w1[o * 6 + 1] * qy + w1[o * 6 + 2] * qz);
    }
    __syncthreads();
    // gather h1
    {
        int kk = t & 63, oc = t >> 6;
        int n = nbr[kk];
        const float* src = &a1t[((size_t)b * 4096 + n) * 64 + oc * 16];
        int dbase = (kk >> 5) * 64 + oc * 16;
#pragma unroll
        for (int i4 = 0; i4 < 4; i4++) {
            float4 v = *(const float4*)&src[i4 * 4];
            float4 d = *(const float4*)&dsh[dbase + i4 * 4];
            h1[(oc * 16 + i4 * 4 + 0) * 64 + kk] = fmaxf(v.x + d.x, 0.f);
            h1[(oc * 16 + i4 * 4 + 1) * 64 + kk] = fmaxf(v.y + d.y, 0.f);
            h1[(oc * 16 + i4 * 4 + 2) * 64 + kk] = fmaxf(v.z + d.z, 0.f);
            h1[(oc * 16 + i4 * 4 + 3) * 64 + kk] = fmaxf(v.w + d.w, 0.f);
        }
    }
    int og = t >> 3, kg = t & 7;
    // L2: 64 -> 64, relu
    float acc[2][8];
    {
        int o = og * 2;
        float bb0 = b2[o], bb1 = b2[o + 1];
#pragma unroll
        for (int j = 0; j < 8; j++) { acc[0][j] = bb0; acc[1][j] = bb1; }
        for (int id = t; id < 1024; id += 256) {  // stage chunk 0
            int c = id & 15, oo = id >> 4;
            wt[0][c * 68 + oo] = w2[oo * 64 + c];
        }
        __syncthreads();
        for (int ch = 0; ch < 4; ch++) {
            if (ch < 3) {
                int c0n = (ch + 1) * 16, nb = (ch + 1) & 1;
                for (int id = t; id < 1024; id += 256) {
                    int c = id & 15, oo = id >> 4;
                    wt[nb][c * 68 + oo] = w2[oo * 64 + c0n + c];
                }
            }
            const float* wb = wt[ch & 1];
#pragma unroll
            for (int cc = 0; cc < 16; cc++) {
                float2 w = *(const float2*)&wb[cc * 68 + og * 2];
                const float* f = &h1[(ch * 16 + cc) * 64 + kg * 8];
                float4 fa = *(const float4*)&f[0];
                float4 fb = *(const float4*)&f[4];
                float fl[8] = {fa.x, fa.y, fa.z, fa.w, fb.x, fb.y, fb.z, fb.w};
#pragma unroll
                for (int j = 0; j < 8; j++) {
                    acc[0][j] += w.x * fl[j];
                    acc[1][j] += w.y * fl[j];
                }
            }
            __syncthreads();
        }
        // store h2 (relu)
#pragma unroll
        for (int oi = 0; oi < 2; oi++) {
            float4 s0, s1;
            s0.x = fmaxf(acc[oi][0], 0.f); s0.y = fmaxf(acc[oi][1], 0.f);
            s0.z = fmaxf(acc[oi][2], 0.f); s0.w = fmaxf(acc[oi][3], 0.f);
            s1.x = fmaxf(acc[oi][4], 0.f); s1.y = fmaxf(acc[oi][5], 0.f);
            s1.z = fmaxf(acc[oi][6], 0.f); s1.w = fmaxf(acc[oi][7], 0.f);
            *(float4*)&h2[(o + oi) * 64 + kg * 8] = s0;
            *(float4*)&h2[(o + oi) * 64 + kg * 8 + 4] = s1;
        }
    }
    // L3: 64 -> 128, no relu, max over 8 cols per thread
    {
        int o3 = og * 4;
        float acc3[4][8];
#pragma unroll
        for (int oi = 0; oi < 4; oi++) {
            float bv = b3[o3 + oi];
#pragma unroll
            for (int j = 0; j < 8; j++) acc3[oi][j] = bv;
        }
        for (int id = t; id < 2048; id += 256) {  // stage chunk 0
            int c = id & 15, oo = id >> 4;
            wt[0][c * 132 + oo] = w3[oo * 64 + c];
        }
        __syncthreads();
        for (int ch = 0; ch < 4; ch++) {
            if (ch < 3) {
                int c0n = (ch + 1) * 16, nb = (ch + 1) & 1;
                for (int id = t; id < 2048; id += 256) {
                    int c = id & 15, oo = id >> 4;
                    wt[nb][c * 132 + oo] = w3[oo * 64 + c0n + c];
                }
            }
            const float* wb = wt[ch & 1];
#pragma unroll
            for (int cc = 0; cc < 16; cc++) {
                float4 w = *(const float4*)&wb[cc * 132 + o3];
                float wl[4] = {w.x, w.y, w.z, w.w};
                const float* f = &h2[(ch * 16 + cc) * 64 + kg * 8];
                float4 fa = *(const float4*)&f[0];
                float4 fb = *(const float4*)&f[4];
                float fl[8] = {fa.x, fa.y, fa.z, fa.w, fb.x, fb.y, fb.z, fb.w};
#pragma unroll
                for (int oi = 0; oi < 4; oi++)
#pragma unroll
                    for (int j = 0; j < 8; j++) acc3[oi][j] += wl[oi] * fl[j];
            }
            __syncthreads();
        }
#pragma unroll
        for (int oi = 0; oi < 4; oi++) {
            float mm = acc3[oi][0];
#pragma unroll
            for (int j = 1; j < 8; j++) mm = fmaxf(mm, acc3[oi][j]);
            mx[(o3 + oi) * 9 + kg] = mm;
        }
    }
    __syncthreads();
    {
        int o = t & 127, ps = t >> 7;
        const float* mr = &mx[o * 9 + ps * 4];
        float v = fmaxf(fmaxf(mr[0], mr[1]), fmaxf(mr[2], mr[3]));
        p1[((size_t)b * 128 + o) * 512 + p0 + ps] = v;
    }
}

// ---------------------------------------------------------------------------
// SA2 precompute: A2t[b][n][o] = b1[o] + sum_c w1[o][c]*[xyz;p1][b][c][n], n<512.
// Grid 32*4 (128-n tiles), 256 thr, 4o x 16n register tiles, dbuf staging.
// ---------------------------------------------------------------------------
__global__ __launch_bounds__(256) void sa2_pre_kernel(
    const float* __restrict__ x, const float* __restrict__ p1,
    const float* __restrict__ w1, const float* __restrict__ b1,
    float* __restrict__ a2t) {
    int bid = blockIdx.x;
    int b = bid >> 2, nt = bid & 3, n0 = nt << 7;
    __shared__ float ins[2][16 * 128];
    __shared__ float wt[2][16 * 132];
    const float* xb = x + (size_t)b * 24576;
    const float* p1b = p1 + (size_t)b * 65536;
    int t = threadIdx.x;
    int og = t >> 3, pg = t & 7;
    int o0 = og * 4;
    float acc[4][16];
    {
        float bl[4] = {b1[o0], b1[o0 + 1], b1[o0 + 2], b1[o0 + 3]};
#pragma unroll
        for (int oi = 0; oi < 4; oi++)
#pragma unroll
            for (int j = 0; j < 16; j++) acc[oi][j] = bl[oi];
    }
    // stage chunk 0 (cs = 16)
    for (int id = t; id < 16 * 128; id += 256) {
        int n = id & 127, c = id >> 7;
        ins[0][c * 128 + n] = (c < 3) ? xb[c * 4096 + n0 + n]
                                      : p1b[(size_t)(c - 3) * 512 + n0 + n];
    }
    for (int id = t; id < 2048; id += 256) {
        int c = id & 15, oo = id >> 4;
        wt[0][c * 132 + oo] = w1[oo * 131 + c];
    }
    __syncthreads();
    for (int ch = 0; ch < 9; ch++) {
        int cs = (ch == 8) ? 3 : 16;
        if (ch < 8) {
            int c0n = (ch + 1) * 16;
            int csn = (ch == 7) ? 3 : 16;
            int nb = (ch + 1) & 1;
            for (int id = t; id < csn * 128; id += 256) {
                int n = id & 127, c = id >> 7;
                int cg = c0n + c;
                ins[nb][c * 128 + n] = (cg < 3) ? xb[cg * 4096 + n0 + n]
                                                : p1b[(size_t)(cg - 3) * 512 + n0 + n];
            }
            for (int id = t; id < 2048; id += 256) {
                int c = id & 15, oo = id >> 4;
                if (c < csn) wt[nb][c * 132 + oo] = w1[oo * 131 + c0n + c];
            }
        }
        const float* wb = wt[ch & 1];
        const float* ib = ins[ch & 1];
        for (int cc = 0; cc < cs; cc++) {
            float4 w = *(const float4*)&wb[cc * 132 + o0];
            float wl[4] = {w.x, w.y, w.z, w.w};
#pragma unroll
            for (int c4 = 0; c4 < 4; c4++) {
                float4 fv = *(const float4*)&ib[cc * 128 + pg * 4 + c4 * 32];
                float fl[4] = {fv.x, fv.y, fv.z, fv.w};
#pragma unroll
                for (int j = 0; j < 4; j++)
#pragma unroll
                    for (int oi = 0; oi < 4; oi++) acc[oi][c4 * 4 + j] += wl[oi] * fl[j];
            }
        }
        __syncthreads();
    }
#pragma unroll
    for (int c4 = 0; c4 < 4; c4++)
#pragma unroll
        for (int j = 0; j < 4; j++) {
            int n = n0 + pg * 4 + c4 * 32 + j;
            float4 v;
            v.x = acc[0][c4 * 4 + j]; v.y = acc[1][c4 * 4 + j];
            v.z = acc[2][c4 * 4 + j]; v.w = acc[3][c4 * 4 + j];
            *(float4*)&a2t[((size_t)b * 512 + n) * 128 + o0] = v;
        }
}

// ---------------------------------------------------------------------------
// SA2 MLP: h1 = relu(A2t[nbr] + D2[p]); L2 128->128 relu; L3 128->256; max.
// One block per (b,p), k=64 in two halves of 32. 256 thr.
// ---------------------------------------------------------------------------
__global__ __launch_bounds__(256) void sa2_mlp_kernel(
    const float* __restrict__ x, const float* __restrict__ a2t,
    const int* __restrict__ idx2, const float* __restrict__ w1,
    const float* __restrict__ w2, const float* __restrict__ b2,
    const float* __restrict__ w3, const float* __restrict__ b3,
    float* __restrict__ p2) {
    int bp = blockIdx.x;  // 32*128
    int b = bp >> 7, p = bp & 127;
    __shared__ float h1[128 * 32];
    __shared__ float h2[128 * 32];
    __shared__ float wt[2][16 * 132];
    __shared__ float mxs[256 * 4];
    __shared__ float dsh[128];
    __shared__ int nbr[64];
    const float* xb = x + (size_t)b * 24576;
    int t = threadIdx.x;
    if (t < 64) nbr[t] = idx2[((size_t)b * 128 + p) * 64 + t];
    if (t < 128) {
        float qx = xb[p], qy = xb[4096 + p], qz = xb[8192 + p];
        dsh[t] = -(w1[t * 131 + 0] * qx + w1[t * 131 + 1] * qy + w1[t * 131 + 2] * qz);
    }
    for (int i = t; i < 1024; i += 256) mxs[i] = -FLT_BIG;
    __syncthreads();
    int og = t >> 2, kg = t & 3;
    int o2 = og * 2;
    for (int half = 0; half < 2; ++half) {
        // gather h1
        {
            int kk = t & 31, oc = t >> 5;
            int n = nbr[half * 32 + kk];
            const float* src = &a2t[((size_t)b * 512 + n) * 128 + oc * 16];
#pragma unroll
            for (int i4 = 0; i4 < 4; i4++) {
                float4 v = *(const float4*)&src[i4 * 4];
                float4 d = *(const float4*)&dsh[oc * 16 + i4 * 4];
                h1[(oc * 16 + i4 * 4 + 0) * 32 + kk] = fmaxf(v.x + d.x, 0.f);
                h1[(oc * 16 + i4 * 4 + 1) * 32 + kk] = fmaxf(v.y + d.y, 0.f);
                h1[(oc * 16 + i4 * 4 + 2) * 32 + kk] = fmaxf(v.z + d.z, 0.f);
                h1[(oc * 16 + i4 * 4 + 3) * 32 + kk] = fmaxf(v.w + d.w, 0.f);
            }
        }
        for (int id = t; id < 2048; id += 256) {  // stage L2 chunk 0
            int c = id & 15, oo = id >> 4;
            wt[0][c * 132 + oo] = w2[oo * 128 + c];
        }
        __syncthreads();
        // L2: 128 -> 128, relu
        float acc[2][8];
        {
            float bb0 = b2[o2], bb1 = b2[o2 + 1];
#pragma unroll
            for (int j = 0; j < 8; j++) { acc[0][j] = bb0; acc[1][j] = bb1; }
            for (int ch = 0; ch < 8; ch++) {
                if (ch < 7) {
                    int c0n = (ch + 1) * 16, nb = (ch + 1) & 1;
                    for (int id = t; id < 2048; id += 256) {
                        int c = id & 15, oo = id >> 4;
                        wt[nb][c * 132 + oo] = w2[oo * 128 + c0n + c];
                    }
                }
                const float* wb = wt[ch & 1];
#pragma unroll
                for (int cc = 0; cc < 16; cc++) {
                    float2 w = *(const float2*)&wb[cc * 132 + o2];
                    const float* f = &h1[(ch * 16 + cc) * 32 + kg * 8];
                    float4 fa = *(const float4*)&f[0];
                    float4 fb = *(const float4*)&f[4];
                    float fl[8] = {fa.x, fa.y, fa.z, fa.w, fb.x, fb.y, fb.z, fb.w};
#pragma unroll
                    for (int j = 0; j < 8; j++) {
                        acc[0][j] += w.x * fl[j];
                        acc[1][j] += w.y * fl[j];
                    }
                }
                __syncthreads();
            }
        }
        // store h2 (relu)
#pragma unroll
        for (int oi = 0; oi < 2; oi++) {
            float4 s0, s1;
            s0.x = fmaxf(acc[oi][0], 0.f); s0.y = fmaxf(acc[oi][1], 0.f);
            s0.z = fmaxf(acc[oi][2], 0.f); s0.w = fmaxf(acc[oi][3], 0.f);
            s1.x = fmaxf(acc[oi][4], 0.f); s1.y = fmaxf(acc[oi][5], 0.f);
            s1.z = fmaxf(acc[oi][6], 0.f); s1.w = fmaxf(acc[oi][7], 0.f);
            *(float4*)&h2[(o2 + oi) * 32 + kg * 8] = s0;
            *(float4*)&h2[(o2 + oi) * 32 + kg * 8 + 4] = s1;
        }
        // L3: 128 -> 256 in two 128-o passes, no relu, running max
        for (int pass = 0; pass < 2; pass++) {
            for (int id = t; id < 2048; id += 256) {  // stage chunk 0
                int c = id & 15, oo = id >> 4;
                wt[0][c * 132 + oo] = w3[(size_t)(pass * 128 + oo) * 128 + c];
            }
            __syncthreads();
            float acc3[2][8];
            {
                float bb0 = b3[pass * 128 + o2], bb1 = b3[pass * 128 + o2 + 1];
#pragma unroll
                for (int j = 0; j < 8; j++) { acc3[0][j] = bb0; acc3[1][j] = bb1; }
            }
            for (int ch = 0; ch < 8; ch++) {
                if (ch < 7) {
                    int c0n = (ch + 1) * 16, nb = (ch + 1) & 1;
                    for (int id = t; id < 2048; id += 256) {
                        int c = id & 15, oo = id >> 4;
                        wt[nb][c * 132 + oo] = w3[(size_t)(pass * 128 + oo) * 128 + c0n + c];
                    }
                }
                const float* wb = wt[ch & 1];
#pragma unroll
                for (int cc = 0; cc < 16; cc++) {
                    float2 w = *(const float2*)&wb[cc * 132 + o2];
                    const float* f = &h2[(ch * 16 + cc) * 32 + kg * 8];
                    float4 fa = *(const float4*)&f[0];
                    float4 fb = *(const float4*)&f[4];
                    float fl[8] = {fa.x, fa.y, fa.z, fa.w, fb.x, fb.y, fb.z, fb.w};
#pragma unroll
                    for (int j = 0; j < 8; j++) {
                        acc3[0][j] += w.x * fl[j];
                        acc3[1][j] += w.y * fl[j];
                    }
                }
                __syncthreads();
            }
#pragma unroll
            for (int oi = 0; oi < 2; oi++) {
                float mm = acc3[oi][0];
#pragma unroll
                for (int j = 1; j < 8; j++) mm = fmaxf(mm, acc3[oi][j]);
                int oidx = (pass * 128 + o2 + oi) * 4 + kg;
                mxs[oidx] = fmaxf(mxs[oidx], mm);
            }
        }
    }
    __syncthreads();
    {
        const float* mr = &mxs[t * 4];
        float v = fmaxf(fmaxf(mr[0], mr[1]), fmaxf(mr[2], mr[3]));
        p2[((size_t)b * 256 + t) * 128 + p] = v;
    }
}

// ---------------------------------------------------------------------------
// SA3 batched GEMM over 128 points: out[b][o][p] = act(bias + W*in).
// 2o x 16k (4x4 interleaved) register tiles, LDS-staged transposed weights.
// reduce=1: fuse max over p into g[b][Cout] instead of storing out.
// ---------------------------------------------------------------------------
__global__ __launch_bounds__(256) void mlp128_kernel(
    const float* __restrict__ in, const float* __restrict__ W,
    const float* __restrict__ bias, float* __restrict__ out,
    int Cin, int Cout, int relu, int wstride, int woff, int reduce) {
    int bid = blockIdx.x;
    int tiles = Cout >> 6;
    int b = bid / tiles, ot = bid - b * tiles;
    int o0t = ot << 6;
    __shared__ float ins[64 * 128];
    __shared__ float wt[2][16 * 68];
    __shared__ float gmx[64 * 8];
    int t = threadIdx.x;
    int og = t >> 3, pg = t & 7;
    int o = o0t + og * 2;
    float acc[2][16];
    {
        float bb0 = bias[o], bb1 = bias[o + 1];
#pragma unroll
        for (int j = 0; j < 16; j++) { acc[0][j] = bb0; acc[1][j] = bb1; }
    }
    int nslab = Cin >> 6;
    for (int sl = 0; sl < nslab; sl++) {
        __syncthreads();
        for (int id = t; id < 2048; id += 256) {
            int p4 = id & 31, c = id >> 5;
            *(float4*)&ins[c * 128 + p4 * 4] =
                *(const float4*)&in[((size_t)b * Cin + sl * 64 + c) * 128 + p4 * 4];
        }
        for (int id = t; id < 1024; id += 256) {
            int c = id & 15, oo = id >> 4;
            wt[0][c * 68 + oo] = W[(size_t)(o0t + oo) * wstride + woff + sl * 64 + c];
        }
        __syncthreads();
        for (int ch = 0; ch < 4; ch++) {
            if (ch < 3) {
                int nb = (ch + 1) & 1;
                for (int id = t; id < 1024; id += 256) {
                    int c = id & 15, oo = id >> 4;
                    wt[nb][c * 68 + oo] =
                        W[(size_t)(o0t + oo) * wstride + woff + sl * 64 + (ch + 1) * 16 + c];
                }
            }
            const float* wb = wt[ch & 1];
#pragma unroll
            for (int cc = 0; cc < 16; cc++) {
                float2 w = *(const float2*)&wb[cc * 68 + og * 2];
                const float* f = &ins[(ch * 16 + cc) * 128 + pg * 4];
#pragma unroll
                for (int c4 = 0; c4 < 4; c4++) {
                    float4 fv = *(const float4*)&f[c4 * 32];
                    float fl[4] = {fv.x, fv.y, fv.z, fv.w};
#pragma unroll
                    for (int j = 0; j < 4; j++) {
                        acc[0][c4 * 4 + j] += w.x * fl[j];
                        acc[1][c4 * 4 + j] += w.y * fl[j];
                    }
                }
            }
            __syncthreads();
        }
    }
    if (!reduce) {
#pragma unroll
        for (int oi = 0; oi < 2; oi++)
#pragma unroll
            for (int c4 = 0; c4 < 4; c4++) {
                float4 v;
                v.x = acc[oi][c4 * 4 + 0]; v.y = acc[oi][c4 * 4 + 1];
                v.z = acc[oi][c4 * 4 + 2]; v.w = acc[oi][c4 * 4 + 3];
                if (relu) {
                    v.x = fmaxf(v.x, 0.f); v.y = fmaxf(v.y, 0.f);
                    v.z = fmaxf(v.z, 0.f); v.w = fmaxf(v.w, 0.f);
                }
                *(float4*)&out[((size_t)b * Cout + o + oi) * 128 + pg * 4 + c4 * 32] = v;
            }
    } else {
#pragma unroll
        for (int oi = 0; oi < 2; oi++) {
            float mm = acc[oi][0];
#pragma unroll
            for (int j = 1; j < 16; j++) mm = fmaxf(mm, acc[oi][j]);
            gmx[(og * 2 + oi) * 8 + pg] = mm;
        }
        __syncthreads();
        if (t < 64) {
            float mm = gmx[t * 8];
#pragma unroll
            for (int i = 1; i < 8; i++) mm = fmaxf(mm, gmx[t * 8 + i]);
            out[(size_t)b * Cout + o0t + t] = mm;
        }
    }
}

// ---------------------------------------------------------------------------
// Head: FC 1024->512->256->40 from pre-reduced g. One block per batch.
// ---------------------------------------------------------------------------
__global__ __launch_bounds__(256) void head_kernel(
    const float* __restrict__ g,
    const float* __restrict__ fw1, const float* __restrict__ fb1,
    const float* __restrict__ fw2, const float* __restrict__ fb2,
    const float* __restrict__ fw3, const float* __restrict__ fb3,
    float* __restrict__ out) {
    int b = blockIdx.x;
    int t = threadIdx.x;
    __shared__ float gs[1024];
    __shared__ float h1[512];
    __shared__ float h2[256];
    for (int i = t; i < 1024; i += 256) gs[i] = g[(size_t)b * 1024 + i];
    __syncthreads();
    for (int oo = 0; oo < 2; oo++) {
        int o = t + oo * 256;
        float acc = fb1[o];
        const float4* wr = (const float4*)&fw1[(size_t)o * 1024];
        for (int c = 0; c < 256; c++) {
            float4 w = wr[c];
            acc += w.x * gs[c * 4] + w.y * gs[c * 4 + 1] + w.z * gs[c * 4 + 2] + w.w * gs[c * 4 + 3];
        }
        h1[o] = fmaxf(acc, 0.f);
    }
    __syncthreads();
    {
        float acc = fb2[t];
        const float4* wr = (const float4*)&fw2[(size_t)t * 512];
        for (int c = 0; c < 128; c++) {
            float4 w = wr[c];
            acc += w.x * h1[c * 4] + w.y * h1[c * 4 + 1] + w.z * h1[c * 4 + 2] + w.w * h1[c * 4 + 3];
        }
        h2[t] = fmaxf(acc, 0.f);
    }
    __syncthreads();
    if (t < 40) {
        float acc = fb3[t];
        const float4* wr = (const float4*)&fw3[(size_t)t * 256];
        for (int c = 0; c < 64; c++) {
            float4 w = wr[c];
            acc += w.x * h2[c * 4] + w.y * h2[c * 4 + 1] + w.z * h2[c * 4 + 2] + w.w * h2[c * 4 + 3];
        }
        out[b * 40 + t] = acc;
    }
}

extern "C" void kernel_launch(void* const* d_in, const int* in_sizes, int n_in,
                              void* d_out, int out_size, void* d_ws, size_t ws_size,
                              hipStream_t stream) {
    const float* x      = (const float*)d_in[0];
    const float* sa1_w1 = (const float*)d_in[1];
    const float* sa1_b1 = (const float*)d_in[2];
    const float* sa1_w2 = (const float*)d_in[3];
    const float* sa1_b2 = (const float*)d_in[4];
    const float* sa1_w3 = (const float*)d_in[5];
    const float* sa1_b3 = (const float*)d_in[6];
    const float* sa2_w1 = (const float*)d_in[7];
    const float* sa2_b1 = (const float*)d_in[8];
    const float* sa2_w2 = (const float*)d_in[9];
    const float* sa2_b2 = (const float*)d_in[10];
    const float* sa2_w3 = (const float*)d_in[11];
    const float* sa2_b3 = (const float*)d_in[12];
    const float* sa3_w1 = (const float*)d_in[13];
    const float* sa3_b1 = (const float*)d_in[14];
    const float* sa3_w2 = (const float*)d_in[15];
    const float* sa3_b2 = (const float*)d_in[16];
    const float* sa3_w3 = (const float*)d_in[17];
    const float* sa3_b3 = (const float*)d_in[18];
    const float* fc1_w  = (const float*)d_in[19];
    const float* fc1_b  = (const float*)d_in[20];
    const float* fc2_w  = (const float*)d_in[21];
    const float* fc2_b  = (const float*)d_in[22];
    const float* fc3_w  = (const float*)d_in[23];
    const float* fc3_b  = (const float*)d_in[24];

    char* ws = (char*)d_ws;
    const size_t MB = 1048576;
    int*   idx1 = (int*)  (ws + 0 * MB);    //  2 MB: (32,512,32)
    float* a1t  = (float*)(ws + 2 * MB);    // 32 MB: (32,4096,64) -- dead after sa1_mlp
    float* p1   = (float*)(ws + 34 * MB);   //  8 MB: (32,128,512) c-major
    int*   idx2 = (int*)  (ws + 42 * MB);   //  1 MB: (32,128,64)
    float* a2t  = (float*)(ws + 2 * MB);    //  8 MB: (32,512,128) overlays dead a1t
    float* p2   = (float*)(ws + 10 * MB);   //  4 MB: (32,256,128)
    float* h1s  = (float*)(ws + 14 * MB);   //  4 MB: (32,256,128)
    float* h2s  = (float*)(ws + 18 * MB);   //  8 MB: (32,512,128)
    float* g    = (float*)(ws + 26 * MB);   //  128 KB: (32,1024)

    knn_select_kernel<<<32 * 512, 256, 0, stream>>>(x, 4096, 32, 512, idx1);
    sa1_pre_kernel<<<32 * 32, 256, 0, stream>>>(x, sa1_w1, sa1_b1, a1t);
    sa1_mlp_kernel<<<32 * 256, 256, 0, stream>>>(x, a1t, idx1, sa1_w1,
                                                 sa1_w2, sa1_b2, sa1_w3, sa1_b3, p1);
    knn_select_kernel<<<32 * 128, 256, 0, stream>>>(x, 512, 64, 128, idx2);
    sa2_pre_kernel<<<32 * 4, 256, 0, stream>>>(x, p1, sa2_w1, sa2_b1, a2t);
    sa2_mlp_kernel<<<32 * 128, 256, 0, stream>>>(x, a2t, idx2, sa2_w1,
                                                 sa2_w2, sa2_b2, sa2_w3, sa2_b3, p2);
    mlp128_kernel<<<32 * 4, 256, 0, stream>>>(p2, sa3_w1, sa3_b1, h1s, 256, 256, 1, 259, 3, 0);
    mlp128_kernel<<<32 * 8, 256, 0, stream>>>(h1s, sa3_w2, sa3_b2, h2s, 256, 512, 1, 256, 0, 0);
    mlp128_kernel<<<32 * 16, 256, 0, stream>>>(h2s, sa3_w3, sa3_b3, g, 512, 1024, 0, 512, 0, 1);
    head_kernel<<<32, 256, 0, stream>>>(g, fc1_w, fc1_b, fc2_w, fc2_b, fc3_w, fc3_b,
                                        (float*)d_out);
}

// Round 3
// 930.139 us; speedup vs baseline: 2.1463x; 1.5034x over previous
//
#include <hip/hip_runtime.h>
#include <hip/hip_bf16.h>

#define FLT_BIG 3.0e38f

// ---------------------------------------------------------------------------
// kNN via radix select (unchanged from round 2).
// ---------------------------------------------------------------------------
__global__ __launch_bounds__(256) void knn_select_kernel(
    const float* __restrict__ x, int N_pts, int K, int P, int* __restrict__ idx_out) {
    int bp = blockIdx.x;
    int b = bp / P, p = bp - b * P;
    const float* xyz = x + (size_t)b * 24576;
    __shared__ unsigned int keys[4096];
    __shared__ unsigned int hist[2048];
    __shared__ unsigned int scanbuf[256];
    __shared__ unsigned int candK[512];
    __shared__ int candI[512];
    __shared__ int outIdx[64];
    __shared__ int sBM[2];
    __shared__ unsigned int cnts[2];
    __shared__ unsigned int wK[4];
    __shared__ int wI[4];
    int t = threadIdx.x;
    for (int i = t; i < 2048; i += 256) hist[i] = 0u;
    if (t < 2) cnts[t] = 0u;
    float qx = xyz[p], qy = xyz[4096 + p], qz = xyz[8192 + p];
    float xs = (qx * qx + qy * qy) + qz * qz;
    __syncthreads();
    for (int n = t; n < N_pts; n += 256) {
        float yx = xyz[n], yy = xyz[4096 + n], yz = xyz[8192 + n];
        float ys = (yx * yx + yy * yy) + yz * yz;
        float dot = (qx * yx + qy * yy) + qz * yz;
        float d2 = (xs + ys) - 2.0f * dot;
        unsigned int k = __float_as_uint(d2);
        k = (k & 0x80000000u) ? ~k : (k | 0x80000000u);
        keys[n] = k;
        atomicAdd(&hist[k >> 21], 1u);
    }
    __syncthreads();
    unsigned int h8[8], mysum = 0u;
#pragma unroll
    for (int i = 0; i < 8; i++) { h8[i] = hist[t * 8 + i]; mysum += h8[i]; }
    scanbuf[t] = mysum;
    __syncthreads();
    for (int s = 1; s < 256; s <<= 1) {
        unsigned int v = (t >= s) ? scanbuf[t - s] : 0u;
        __syncthreads();
        scanbuf[t] += v;
        __syncthreads();
    }
    unsigned int cum = scanbuf[t] - mysum;
#pragma unroll
    for (int i = 0; i < 8; i++) {
        if (cum < (unsigned)K && cum + h8[i] >= (unsigned)K) { sBM[0] = t * 8 + i; sBM[1] = (int)cum; }
        cum += h8[i];
    }
    __syncthreads();
    int B = sBM[0], m = sBM[1], r = K - m;
    for (int n = t; n < N_pts; n += 256) {
        unsigned int k = keys[n];
        int bin = (int)(k >> 21);
        if (bin < B) {
            outIdx[atomicAdd(&cnts[0], 1u)] = n;
        } else if (bin == B) {
            unsigned int ci = atomicAdd(&cnts[1], 1u);
            if (ci < 512u) { candK[ci] = k; candI[ci] = n; }
        }
    }
    __syncthreads();
    int nc = (int)cnts[1];
    if (nc <= 512) {
        for (int ci = t; ci < nc; ci += 256) {
            unsigned int ki = candK[ci];
            int ii = candI[ci];
            int rank = 0;
            for (int j = 0; j < nc; j++) {
                unsigned int kj = candK[j];
                rank += (kj < ki || (kj == ki && candI[j] < ii)) ? 1 : 0;
            }
            if (rank < r) outIdx[m + rank] = ii;
        }
    } else {
        for (int rr = 0; rr < r; ++rr) {
            unsigned int best = 0xFFFFFFFFu;
            int bi = 0x7fffffff;
            for (int n = t; n < N_pts; n += 256) {
                unsigned int k2 = keys[n];
                if ((int)(k2 >> 21) == B && (k2 < best || (k2 == best && n < bi))) { best = k2; bi = n; }
            }
#pragma unroll
            for (int s = 32; s > 0; s >>= 1) {
                unsigned int ov = (unsigned int)__shfl_down((int)best, s);
                int oi = __shfl_down(bi, s);
                if (ov < best || (ov == best && oi < bi)) { best = ov; bi = oi; }
            }
            int lane = t & 63, wv = t >> 6;
            if (lane == 0) { wK[wv] = best; wI[wv] = bi; }
            __syncthreads();
            if (t == 0) {
                unsigned int bb = wK[0];
                int ii = wI[0];
                for (int w = 1; w < 4; ++w)
                    if (wK[w] < bb || (wK[w] == bb && wI[w] < ii)) { bb = wK[w]; ii = wI[w]; }
                outIdx[m + rr] = ii;
                keys[ii] = 0xFFFFFFFFu;
            }
            __syncthreads();
        }
    }
    __syncthreads();
    if (t < K) idx_out[(size_t)bp * K + t] = outIdx[t];
}

// ---------------------------------------------------------------------------
// SA1 precompute: A1t[b][n][o] = b1[o] + sum_c w1[o][c]*x[b][c][n] (c=0..5).
// ---------------------------------------------------------------------------
__global__ __launch_bounds__(256) void sa1_pre_kernel(
    const float* __restrict__ x, const float* __restrict__ w1, const float* __restrict__ b1,
    float* __restrict__ a1t) {
    int bid = blockIdx.x;
    int b = bid >> 5, nt = bid & 31, n0 = nt << 7;
    __shared__ float xsh[6 * 128];
    __shared__ float wt[6 * 68];
    const float* xb = x + (size_t)b * 24576;
    int t = threadIdx.x;
    for (int id = t; id < 768; id += 256) {
        int c = id >> 7, n = id & 127;
        xsh[c * 128 + n] = xb[c * 4096 + n0 + n];
    }
    for (int id = t; id < 384; id += 256) {
        int c = id >> 6, o = id & 63;
        wt[c * 68 + o] = w1[o * 6 + c];
    }
    __syncthreads();
    int o = t & 63, ng = t >> 6;
    float acc[32];
    float bias = b1[o];
#pragma unroll
    for (int j = 0; j < 32; j++) acc[j] = bias;
    for (int c = 0; c < 6; c++) {
        float w = wt[c * 68 + o];
        const float* f = &xsh[c * 128 + ng * 32];
#pragma unroll
        for (int j = 0; j < 32; j++) acc[j] += w * f[j];
    }
#pragma unroll
    for (int j = 0; j < 32; j++)
        a1t[((size_t)b * 4096 + n0 + ng * 32 + j) * 64 + o] = acc[j];
}

// ---------------------------------------------------------------------------
// SA1 fused: gather h1 = relu(A1t[nbr]+D) -> L2 (64->64 relu) -> L3 (64->128)
// -> max over k=32. Block = 2 queries (64 cols), 256 thr, 24.6KB LDS.
// smem aliases: phase1 {H1[16][64], W2T[16][64], H2[64][64]};
//               phase2 {W3T[16][128] over H1+W2T, H2}; MX[1024] over W3T.
// ---------------------------------------------------------------------------
__global__ __launch_bounds__(256) void sa1_fused_kernel(
    const float* __restrict__ x, const float* __restrict__ a1t,
    const int* __restrict__ idx1, const float* __restrict__ w1,
    const float* __restrict__ w2, const float* __restrict__ b2,
    const float* __restrict__ w3, const float* __restrict__ b3,
    float* __restrict__ p1) {
    int bp = blockIdx.x;  // 32*256
    int b = bp >> 8, pp = bp & 255, p0 = pp * 2;
    __shared__ float smem[6144];
    __shared__ int nbr[64];
    __shared__ float dshq[2][64];
    float* H1 = smem;            // 1024
    float* W2T = smem + 1024;    // 1024
    float* H2 = smem + 2048;     // 4096
    float* W3T = smem;           // 2048 (aliases H1+W2T)
    float* MX = smem;            // 1024 (aliases W3T, after final sync)
    const float* xb = x + (size_t)b * 24576;
    int t = threadIdx.x;
    if (t < 64) nbr[t] = idx1[((size_t)b * 512 + p0) * 32 + t];
    if (t < 128) {
        int qi = t >> 6, c = t & 63;
        float qx = xb[p0 + qi], qy = xb[4096 + p0 + qi], qz = xb[8192 + p0 + qi];
        dshq[qi][c] = -(w1[c * 6 + 0] * qx + w1[c * 6 + 1] * qy + w1[c * 6 + 2] * qz);
    }
    __syncthreads();
    // ---- phase 1: L2 (64 -> 64, relu), K=64 in 4 slabs of 16
    {
        int og = t >> 4, jg = t & 15;
        int o0 = og * 4, j0 = jg * 4;
        float acc2[4][4];
#pragma unroll
        for (int oi = 0; oi < 4; oi++) {
            float bv = b2[o0 + oi];
#pragma unroll
            for (int ji = 0; ji < 4; ji++) acc2[oi][ji] = bv;
        }
        int gj = t & 63, gch = t >> 6;
        int n = nbr[gj], qi = gj >> 5;
        const float* arow = &a1t[((size_t)b * 4096 + n) * 64];
        for (int sl = 0; sl < 4; sl++) {
            int c0 = sl * 16;
            {   // gather 4 channels of h1 for col gj
                float4 v = *(const float4*)&arow[c0 + gch * 4];
                const float* d = &dshq[qi][c0 + gch * 4];
                H1[(gch * 4 + 0) * 64 + gj] = fmaxf(v.x + d[0], 0.f);
                H1[(gch * 4 + 1) * 64 + gj] = fmaxf(v.y + d[1], 0.f);
                H1[(gch * 4 + 2) * 64 + gj] = fmaxf(v.z + d[2], 0.f);
                H1[(gch * 4 + 3) * 64 + gj] = fmaxf(v.w + d[3], 0.f);
            }
            {   // stage w2 slab transposed
                float4 v = *(const float4*)&w2[gj * 64 + c0 + gch * 4];
                W2T[(gch * 4 + 0) * 64 + gj] = v.x;
                W2T[(gch * 4 + 1) * 64 + gj] = v.y;
                W2T[(gch * 4 + 2) * 64 + gj] = v.z;
                W2T[(gch * 4 + 3) * 64 + gj] = v.w;
            }
            __syncthreads();
#pragma unroll
            for (int cc = 0; cc < 16; cc++) {
                float4 w = *(const float4*)&W2T[cc * 64 + o0];
                float4 f = *(const float4*)&H1[cc * 64 + j0];
                float wl[4] = {w.x, w.y, w.z, w.w};
                float fl[4] = {f.x, f.y, f.z, f.w};
#pragma unroll
                for (int oi = 0; oi < 4; oi++)
#pragma unroll
                    for (int ji = 0; ji < 4; ji++) acc2[oi][ji] += wl[oi] * fl[ji];
            }
            __syncthreads();
        }
#pragma unroll
        for (int oi = 0; oi < 4; oi++) {
            float4 s;
            s.x = fmaxf(acc2[oi][0], 0.f); s.y = fmaxf(acc2[oi][1], 0.f);
            s.z = fmaxf(acc2[oi][2], 0.f); s.w = fmaxf(acc2[oi][3], 0.f);
            *(float4*)&H2[(o0 + oi) * 64 + j0] = s;
        }
    }
    __syncthreads();
    // ---- phase 2: L3 (64 -> 128), K=64 in 4 slabs of 16, + max over k=32
    {
        int og = t >> 3, jg = t & 7;
        int o0 = og * 4, j0 = jg * 8;
        float acc3[4][8];
#pragma unroll
        for (int oi = 0; oi < 4; oi++) {
            float bv = b3[o0 + oi];
#pragma unroll
            for (int ji = 0; ji < 8; ji++) acc3[oi][ji] = bv;
        }
        int so = t & 127, shf = t >> 7;
        for (int sl = 0; sl < 4; sl++) {
            int c0 = sl * 16;
            {   // stage w3 slab transposed
                float4 v0 = *(const float4*)&w3[so * 64 + c0 + shf * 8];
                float4 v1 = *(const float4*)&w3[so * 64 + c0 + shf * 8 + 4];
                W3T[(shf * 8 + 0) * 128 + so] = v0.x;
                W3T[(shf * 8 + 1) * 128 + so] = v0.y;
                W3T[(shf * 8 + 2) * 128 + so] = v0.z;
                W3T[(shf * 8 + 3) * 128 + so] = v0.w;
                W3T[(shf * 8 + 4) * 128 + so] = v1.x;
                W3T[(shf * 8 + 5) * 128 + so] = v1.y;
                W3T[(shf * 8 + 6) * 128 + so] = v1.z;
                W3T[(shf * 8 + 7) * 128 + so] = v1.w;
            }
            __syncthreads();
#pragma unroll
            for (int cc = 0; cc < 16; cc++) {
                float4 w = *(const float4*)&W3T[cc * 128 + o0];
                float4 f0 = *(const float4*)&H2[(c0 + cc) * 64 + j0];
                float4 f1 = *(const float4*)&H2[(c0 + cc) * 64 + j0 + 4];
                float wl[4] = {w.x, w.y, w.z, w.w};
                float fl[8] = {f0.x, f0.y, f0.z, f0.w, f1.x, f1.y, f1.z, f1.w};
#pragma unroll
                for (int oi = 0; oi < 4; oi++)
#pragma unroll
                    for (int ji = 0; ji < 8; ji++) acc3[oi][ji] += wl[oi] * fl[ji];
            }
            __syncthreads();
        }
        // per-thread max over its 8 cols (all within one query group of 32)
#pragma unroll
        for (int oi = 0; oi < 4; oi++) {
            float m = acc3[oi][0];
#pragma unroll
            for (int ji = 1; ji < 8; ji++) m = fmaxf(m, acc3[oi][ji]);
            MX[(o0 + oi) * 8 + jg] = m;
        }
    }
    __syncthreads();
    {
        int o = t & 127, grp = t >> 7;
        const float* mr = &MX[o * 8 + grp * 4];
        float v = fmaxf(fmaxf(mr[0], mr[1]), fmaxf(mr[2], mr[3]));
        p1[((size_t)b * 128 + o) * 512 + p0 + grp] = v;
    }
}

// ---------------------------------------------------------------------------
// SA2 precompute: A2t[b][n][o] = b1[o] + sum_c w1[o][c]*[xyz;p1][b][c][n].
// ---------------------------------------------------------------------------
__global__ __launch_bounds__(256) void sa2_pre_kernel(
    const float* __restrict__ x, const float* __restrict__ p1,
    const float* __restrict__ w1, const float* __restrict__ b1,
    float* __restrict__ a2t) {
    int bid = blockIdx.x;
    int b = bid >> 2, nt = bid & 3, n0 = nt << 7;
    __shared__ float ins[2][16 * 128];
    __shared__ float wt[2][16 * 132];
    const float* xb = x + (size_t)b * 24576;
    const float* p1b = p1 + (size_t)b * 65536;
    int t = threadIdx.x;
    int og = t >> 3, pg = t & 7;
    int o0 = og * 4;
    float acc[4][16];
    {
        float bl[4] = {b1[o0], b1[o0 + 1], b1[o0 + 2], b1[o0 + 3]};
#pragma unroll
        for (int oi = 0; oi < 4; oi++)
#pragma unroll
            for (int j = 0; j < 16; j++) acc[oi][j] = bl[oi];
    }
    for (int id = t; id < 16 * 128; id += 256) {
        int n = id & 127, c = id >> 7;
        ins[0][c * 128 + n] = (c < 3) ? xb[c * 4096 + n0 + n]
                                      : p1b[(size_t)(c - 3) * 512 + n0 + n];
    }
    for (int id = t; id < 2048; id += 256) {
        int c = id & 15, oo = id >> 4;
        wt[0][c * 132 + oo] = w1[oo * 131 + c];
    }
    __syncthreads();
    for (int ch = 0; ch < 9; ch++) {
        int cs = (ch == 8) ? 3 : 16;
        if (ch < 8) {
            int c0n = (ch + 1) * 16;
            int csn = (ch == 7) ? 3 : 16;
            int nb = (ch + 1) & 1;
            for (int id = t; id < csn * 128; id += 256) {
                int n = id & 127, c = id >> 7;
                int cg = c0n + c;
                ins[nb][c * 128 + n] = (cg < 3) ? xb[cg * 4096 + n0 + n]
                                                : p1b[(size_t)(cg - 3) * 512 + n0 + n];
            }
            for (int id = t; id < 2048; id += 256) {
                int c = id & 15, oo = id >> 4;
                if (c < csn) wt[nb][c * 132 + oo] = w1[oo * 131 + c0n + c];
            }
        }
        const float* wb = wt[ch & 1];
        const float* ib = ins[ch & 1];
        for (int cc = 0; cc < cs; cc++) {
            float4 w = *(const float4*)&wb[cc * 132 + o0];
            float wl[4] = {w.x, w.y, w.z, w.w};
#pragma unroll
            for (int c4 = 0; c4 < 4; c4++) {
                float4 fv = *(const float4*)&ib[cc * 128 + pg * 4 + c4 * 32];
                float fl[4] = {fv.x, fv.y, fv.z, fv.w};
#pragma unroll
                for (int j = 0; j < 4; j++)
#pragma unroll
                    for (int oi = 0; oi < 4; oi++) acc[oi][c4 * 4 + j] += wl[oi] * fl[j];
            }
        }
        __syncthreads();
    }
#pragma unroll
    for (int c4 = 0; c4 < 4; c4++)
#pragma unroll
        for (int j = 0; j < 4; j++) {
            int n = n0 + pg * 4 + c4 * 32 + j;
            float4 v;
            v.x = acc[0][c4 * 4 + j]; v.y = acc[1][c4 * 4 + j];
            v.z = acc[2][c4 * 4 + j]; v.w = acc[3][c4 * 4 + j];
            *(float4*)&a2t[((size_t)b * 512 + n) * 128 + o0] = v;
        }
}

// ---------------------------------------------------------------------------
// SA2 fused: gather h1 = relu(A2t[nbr]+D) -> L2 (128->128 relu) ->
// L3 (128->256) -> max over k=64. Block = 1 query (64 cols), 256 thr, 50KB LDS.
// smem aliases: phase1 {H1[16][64], W2T[16][128], H2[128][64]};
//               phase2 {W3T[16][256] over H1+W2T, H2}; MX[1024] over W3T.
// ---------------------------------------------------------------------------
__global__ __launch_bounds__(256) void sa2_fused_kernel(
    const float* __restrict__ x, const float* __restrict__ a2t,
    const int* __restrict__ idx2, const float* __restrict__ w1,
    const float* __restrict__ w2, const float* __restrict__ b2,
    const float* __restrict__ w3, const float* __restrict__ b3,
    float* __restrict__ p2) {
    int bp = blockIdx.x;  // 32*128
    int b = bp >> 7, p = bp & 127;
    __shared__ float smem[12288];
    __shared__ int nbr[64];
    __shared__ float dshq[128];
    float* H1 = smem;            // 1024 (16x64)
    float* W2T = smem + 1024;    // 2048 (16x128)
    float* H2 = smem + 4096;     // 8192 (128x64)
    float* W3T = smem;           // 4096 (16x256, aliases H1+W2T)
    float* MX = smem;            // 1024 (aliases W3T after final sync)
    const float* xb = x + (size_t)b * 24576;
    int t = threadIdx.x;
    if (t < 64) nbr[t] = idx2[((size_t)b * 128 + p) * 64 + t];
    if (t < 128) {
        float qx = xb[p], qy = xb[4096 + p], qz = xb[8192 + p];
        dshq[t] = -(w1[t * 131 + 0] * qx + w1[t * 131 + 1] * qy + w1[t * 131 + 2] * qz);
    }
    __syncthreads();
    // ---- phase 1: L2 (128 -> 128, relu), K=128 in 8 slabs of 16
    {
        int og = t >> 3, jg = t & 7;
        int o0 = og * 4, j0 = jg * 8;
        float acc2[4][8];
#pragma unroll
        for (int oi = 0; oi < 4; oi++) {
            float bv = b2[o0 + oi];
#pragma unroll
            for (int ji = 0; ji < 8; ji++) acc2[oi][ji] = bv;
        }
        int gj = t & 63, gch = t >> 6;       // gather: col gj, 4 channels
        int n = nbr[gj];
        const float* arow = &a2t[((size_t)b * 512 + n) * 128];
        int so = t & 127, shf = t >> 7;      // w2 stage: row so, 8 channels
        for (int sl = 0; sl < 8; sl++) {
            int c0 = sl * 16;
            {
                float4 v = *(const float4*)&arow[c0 + gch * 4];
                const float* d = &dshq[c0 + gch * 4];
                H1[(gch * 4 + 0) * 64 + gj] = fmaxf(v.x + d[0], 0.f);
                H1[(gch * 4 + 1) * 64 + gj] = fmaxf(v.y + d[1], 0.f);
                H1[(gch * 4 + 2) * 64 + gj] = fmaxf(v.z + d[2], 0.f);
                H1[(gch * 4 + 3) * 64 + gj] = fmaxf(v.w + d[3], 0.f);
            }
            {
                float4 v0 = *(const float4*)&w2[so * 128 + c0 + shf * 8];
                float4 v1 = *(const float4*)&w2[so * 128 + c0 + shf * 8 + 4];
                W2T[(shf * 8 + 0) * 128 + so] = v0.x;
                W2T[(shf * 8 + 1) * 128 + so] = v0.y;
                W2T[(shf * 8 + 2) * 128 + so] = v0.z;
                W2T[(shf * 8 + 3) * 128 + so] = v0.w;
                W2T[(shf * 8 + 4) * 128 + so] = v1.x;
                W2T[(shf * 8 + 5) * 128 + so] = v1.y;
                W2T[(shf * 8 + 6) * 128 + so] = v1.z;
                W2T[(shf * 8 + 7) * 128 + so] = v1.w;
            }
            __syncthreads();
#pragma unroll
            for (int cc = 0; cc < 16; cc++) {
                float4 w = *(const float4*)&W2T[cc * 128 + o0];
                float4 f0 = *(const float4*)&H1[cc * 64 + j0];
                float4 f1 = *(const float4*)&H1[cc * 64 + j0 + 4];
                float wl[4] = {w.x, w.y, w.z, w.w};
                float fl[8] = {f0.x, f0.y, f0.z, f0.w, f1.x, f1.y, f1.z, f1.w};
#pragma unroll
                for (int oi = 0; oi < 4; oi++)
#pragma unroll
                    for (int ji = 0; ji < 8; ji++) acc2[oi][ji] += wl[oi] * fl[ji];
            }
            __syncthreads();
        }
#pragma unroll
        for (int oi = 0; oi < 4; oi++) {
            float4 s0, s1;
            s0.x = fmaxf(acc2[oi][0], 0.f); s0.y = fmaxf(acc2[oi][1], 0.f);
            s0.z = fmaxf(acc2[oi][2], 0.f); s0.w = fmaxf(acc2[oi][3], 0.f);
            s1.x = fmaxf(acc2[oi][4], 0.f); s1.y = fmaxf(acc2[oi][5], 0.f);
            s1.z = fmaxf(acc2[oi][6], 0.f); s1.w = fmaxf(acc2[oi][7], 0.f);
            *(float4*)&H2[(o0 + oi) * 64 + j0] = s0;
            *(float4*)&H2[(o0 + oi) * 64 + j0 + 4] = s1;
        }
    }
    __syncthreads();
    // ---- phase 2: L3 (128 -> 256), K=128 in 8 slabs of 16, + max over k=64
    {
        int og = t >> 2, jg = t & 3;
        int o0 = og * 4, j0 = jg * 16;
        float acc3[4][16];
#pragma unroll
        for (int oi = 0; oi < 4; oi++) {
            float bv = b3[o0 + oi];
#pragma unroll
            for (int ji = 0; ji < 16; ji++) acc3[oi][ji] = bv;
        }
        for (int sl = 0; sl < 8; sl++) {
            int c0 = sl * 16;
            {   // stage w3 slab transposed: row t, 16 channels
                const float* wr = &w3[(size_t)t * 128 + c0];
#pragma unroll
                for (int q = 0; q < 4; q++) {
                    float4 v = *(const float4*)&wr[q * 4];
                    W3T[(q * 4 + 0) * 256 + t] = v.x;
                    W3T[(q * 4 + 1) * 256 + t] = v.y;
                    W3T[(q * 4 + 2) * 256 + t] = v.z;
                    W3T[(q * 4 + 3) * 256 + t] = v.w;
                }
            }
            __syncthreads();
#pragma unroll
            for (int cc = 0; cc < 16; cc++) {
                float4 w = *(const float4*)&W3T[cc * 256 + o0];
                float wl[4] = {w.x, w.y, w.z, w.w};
                const float* f = &H2[(c0 + cc) * 64 + j0];
                float4 fa = *(const float4*)&f[0];
                float4 fb = *(const float4*)&f[4];
                float4 fc = *(const float4*)&f[8];
                float4 fd = *(const float4*)&f[12];
                float fl[16] = {fa.x, fa.y, fa.z, fa.w, fb.x, fb.y, fb.z, fb.w,
                                fc.x, fc.y, fc.z, fc.w, fd.x, fd.y, fd.z, fd.w};
#pragma unroll
                for (int oi = 0; oi < 4; oi++)
#pragma unroll
                    for (int ji = 0; ji < 16; ji++) acc3[oi][ji] += wl[oi] * fl[ji];
            }
            __syncthreads();
        }
#pragma unroll
        for (int oi = 0; oi < 4; oi++) {
            float m = acc3[oi][0];
#pragma unroll
            for (int ji = 1; ji < 16; ji++) m = fmaxf(m, acc3[oi][ji]);
            MX[(o0 + oi) * 4 + jg] = m;
        }
    }
    __syncthreads();
    {
        const float* mr = &MX[t * 4];
        float v = fmaxf(fmaxf(mr[0], mr[1]), fmaxf(mr[2], mr[3]));
        p2[((size_t)b * 256 + t) * 128 + p] = v;
    }
}

// ---------------------------------------------------------------------------
// SA3 batched GEMM over 128 points (unchanged).
// ---------------------------------------------------------------------------
__global__ __launch_bounds__(256) void mlp128_kernel(
    const float* __restrict__ in, const float* __restrict__ W,
    const float* __restrict__ bias, float* __restrict__ out,
    int Cin, int Cout, int relu, int wstride, int woff, int reduce) {
    int bid = blockIdx.x;
    int tiles = Cout >> 6;
    int b = bid / tiles, ot = bid - b * tiles;
    int o0t = ot << 6;
    __shared__ float ins[64 * 128];
    __shared__ float wt[2][16 * 68];
    __shared__ float gmx[64 * 8];
    int t = threadIdx.x;
    int og = t >> 3, pg = t & 7;
    int o = o0t + og * 2;
    float acc[2][16];
    {
        float bb0 = bias[o], bb1 = bias[o + 1];
#pragma unroll
        for (int j = 0; j < 16; j++) { acc[0][j] = bb0; acc[1][j] = bb1; }
    }
    int nslab = Cin >> 6;
    for (int sl = 0; sl < nslab; sl++) {
        __syncthreads();
        for (int id = t; id < 2048; id += 256) {
            int p4 = id & 31, c = id >> 5;
            *(float4*)&ins[c * 128 + p4 * 4] =
                *(const float4*)&in[((size_t)b * Cin + sl * 64 + c) * 128 + p4 * 4];
        }
        for (int id = t; id < 1024; id += 256) {
            int c = id & 15, oo = id >> 4;
            wt[0][c * 68 + oo] = W[(size_t)(o0t + oo) * wstride + woff + sl * 64 + c];
        }
        __syncthreads();
        for (int ch = 0; ch < 4; ch++) {
            if (ch < 3) {
                int nb = (ch + 1) & 1;
                for (int id = t; id < 1024; id += 256) {
                    int c = id & 15, oo = id >> 4;
                    wt[nb][c * 68 + oo] =
                        W[(size_t)(o0t + oo) * wstride + woff + sl * 64 + (ch + 1) * 16 + c];
                }
            }
            const float* wb = wt[ch & 1];
#pragma unroll
            for (int cc = 0; cc < 16; cc++) {
                float2 w = *(const float2*)&wb[cc * 68 + og * 2];
                const float* f = &ins[(ch * 16 + cc) * 128 + pg * 4];
#pragma unroll
                for (int c4 = 0; c4 < 4; c4++) {
                    float4 fv = *(const float4*)&f[c4 * 32];
                    float fl[4] = {fv.x, fv.y, fv.z, fv.w};
#pragma unroll
                    for (int j = 0; j < 4; j++) {
                        acc[0][c4 * 4 + j] += w.x * fl[j];
                        acc[1][c4 * 4 + j] += w.y * fl[j];
                    }
                }
            }
            __syncthreads();
        }
    }
    if (!reduce) {
#pragma unroll
        for (int oi = 0; oi < 2; oi++)
#pragma unroll
            for (int c4 = 0; c4 < 4; c4++) {
                float4 v;
                v.x = acc[oi][c4 * 4 + 0]; v.y = acc[oi][c4 * 4 + 1];
                v.z = acc[oi][c4 * 4 + 2]; v.w = acc[oi][c4 * 4 + 3];
                if (relu) {
                    v.x = fmaxf(v.x, 0.f); v.y = fmaxf(v.y, 0.f);
                    v.z = fmaxf(v.z, 0.f); v.w = fmaxf(v.w, 0.f);
                }
                *(float4*)&out[((size_t)b * Cout + o + oi) * 128 + pg * 4 + c4 * 32] = v;
            }
    } else {
#pragma unroll
        for (int oi = 0; oi < 2; oi++) {
            float mm = acc[oi][0];
#pragma unroll
            for (int j = 1; j < 16; j++) mm = fmaxf(mm, acc[oi][j]);
            gmx[(og * 2 + oi) * 8 + pg] = mm;
        }
        __syncthreads();
        if (t < 64) {
            float mm = gmx[t * 8];
#pragma unroll
            for (int i = 1; i < 8; i++) mm = fmaxf(mm, gmx[t * 8 + i]);
            out[(size_t)b * Cout + o0t + t] = mm;
        }
    }
}

// ---------------------------------------------------------------------------
// Head: FC 1024->512->256->40 (unchanged).
// ---------------------------------------------------------------------------
__global__ __launch_bounds__(256) void head_kernel(
    const float* __restrict__ g,
    const float* __restrict__ fw1, const float* __restrict__ fb1,
    const float* __restrict__ fw2, const float* __restrict__ fb2,
    const float* __restrict__ fw3, const float* __restrict__ fb3,
    float* __restrict__ out) {
    int b = blockIdx.x;
    int t = threadIdx.x;
    __shared__ float gs[1024];
    __shared__ float h1[512];
    __shared__ float h2[256];
    for (int i = t; i < 1024; i += 256) gs[i] = g[(size_t)b * 1024 + i];
    __syncthreads();
    for (int oo = 0; oo < 2; oo++) {
        int o = t + oo * 256;
        float acc = fb1[o];
        const float4* wr = (const float4*)&fw1[(size_t)o * 1024];
        for (int c = 0; c < 256; c++) {
            float4 w = wr[c];
            acc += w.x * gs[c * 4] + w.y * gs[c * 4 + 1] + w.z * gs[c * 4 + 2] + w.w * gs[c * 4 + 3];
        }
        h1[o] = fmaxf(acc, 0.f);
    }
    __syncthreads();
    {
        float acc = fb2[t];
        const float4* wr = (const float4*)&fw2[(size_t)t * 512];
        for (int c = 0; c < 128; c++) {
            float4 w = wr[c];
            acc += w.x * h1[c * 4] + w.y * h1[c * 4 + 1] + w.z * h1[c * 4 + 2] + w.w * h1[c * 4 + 3];
        }
        h2[t] = fmaxf(acc, 0.f);
    }
    __syncthreads();
    if (t < 40) {
        float acc = fb3[t];
        const float4* wr = (const float4*)&fw3[(size_t)t * 256];
        for (int c = 0; c < 64; c++) {
            float4 w = wr[c];
            acc += w.x * h2[c * 4] + w.y * h2[c * 4 + 1] + w.z * h2[c * 4 + 2] + w.w * h2[c * 4 + 3];
        }
        out[b * 40 + t] = acc;
    }
}

extern "C" void kernel_launch(void* const* d_in, const int* in_sizes, int n_in,
                              void* d_out, int out_size, void* d_ws, size_t ws_size,
                              hipStream_t stream) {
    const float* x      = (const float*)d_in[0];
    const float* sa1_w1 = (const float*)d_in[1];
    const float* sa1_b1 = (const float*)d_in[2];
    const float* sa1_w2 = (const float*)d_in[3];
    const float* sa1_b2 = (const float*)d_in[4];
    const float* sa1_w3 = (const float*)d_in[5];
    const float* sa1_b3 = (const float*)d_in[6];
    const float* sa2_w1 = (const float*)d_in[7];
    const float* sa2_b1 = (const float*)d_in[8];
    const float* sa2_w2 = (const float*)d_in[9];
    const float* sa2_b2 = (const float*)d_in[10];
    const float* sa2_w3 = (const float*)d_in[11];
    const float* sa2_b3 = (const float*)d_in[12];
    const float* sa3_w1 = (const float*)d_in[13];
    const float* sa3_b1 = (const float*)d_in[14];
    const float* sa3_w2 = (const float*)d_in[15];
    const float* sa3_b2 = (const float*)d_in[16];
    const float* sa3_w3 = (const float*)d_in[17];
    const float* sa3_b3 = (const float*)d_in[18];
    const float* fc1_w  = (const float*)d_in[19];
    const float* fc1_b  = (const float*)d_in[20];
    const float* fc2_w  = (const float*)d_in[21];
    const float* fc2_b  = (const float*)d_in[22];
    const float* fc3_w  = (const float*)d_in[23];
    const float* fc3_b  = (const float*)d_in[24];

    char* ws = (char*)d_ws;
    const size_t MB = 1048576;
    int*   idx1 = (int*)  (ws + 0 * MB);    //  2 MB: (32,512,32)
    float* a1t  = (float*)(ws + 2 * MB);    // 32 MB: (32,4096,64) -- dead after sa1_fused
    float* p1   = (float*)(ws + 34 * MB);   //  8 MB: (32,128,512) c-major
    int*   idx2 = (int*)  (ws + 42 * MB);   //  1 MB: (32,128,64)
    float* a2t  = (float*)(ws + 2 * MB);    //  8 MB: (32,512,128) overlays dead a1t
    float* p2   = (float*)(ws + 10 * MB);   //  4 MB: (32,256,128)
    float* h1s  = (float*)(ws + 14 * MB);   //  4 MB: (32,256,128)
    float* h2s  = (float*)(ws + 18 * MB);   //  8 MB: (32,512,128)
    float* g    = (float*)(ws + 26 * MB);   //  128 KB: (32,1024)

    knn_select_kernel<<<32 * 512, 256, 0, stream>>>(x, 4096, 32, 512, idx1);
    sa1_pre_kernel<<<32 * 32, 256, 0, stream>>>(x, sa1_w1, sa1_b1, a1t);
    sa1_fused_kernel<<<32 * 256, 256, 0, stream>>>(x, a1t, idx1, sa1_w1,
                                                   sa1_w2, sa1_b2, sa1_w3, sa1_b3, p1);
    knn_select_kernel<<<32 * 128, 256, 0, stream>>>(x, 512, 64, 128, idx2);
    sa2_pre_kernel<<<32 * 4, 256, 0, stream>>>(x, p1, sa2_w1, sa2_b1, a2t);
    sa2_fused_kernel<<<32 * 128, 256, 0, stream>>>(x, a2t, idx2, sa2_w1,
                                                   sa2_w2, sa2_b2, sa2_w3, sa2_b3, p2);
    mlp128_kernel<<<32 * 4, 256, 0, stream>>>(p2, sa3_w1, sa3_b1, h1s, 256, 256, 1, 259, 3, 0);
    mlp128_kernel<<<32 * 8, 256, 0, stream>>>(h1s, sa3_w2, sa3_b2, h2s, 256, 512, 1, 256, 0, 0);
    mlp128_kernel<<<32 * 16, 256, 0, stream>>>(h2s, sa3_w3, sa3_b3, g, 512, 1024, 0, 512, 0, 1);
    head_kernel<<<32, 256, 0, stream>>>(g, fc1_w, fc1_b, fc2_w, fc2_b, fc3_w, fc3_b,
                                        (float*)d_out);
}